// Round 1
// baseline (369.854 us; speedup 1.0000x reference)
//
#include <hip/hip_runtime.h>
#include <hip/hip_bf16.h>

typedef unsigned short u16;
typedef unsigned int u32;
typedef __bf16 bf16x8 __attribute__((ext_vector_type(8)));
typedef float f32x4 __attribute__((ext_vector_type(4)));

// N_NODES=131072, IN_CHANNELS=256, NUM_PROJ=256, NUM_QUANT=256, NUM_GRAPHS=256
// nodes_per_graph = 512; scale = sqrt(256*256) = 256.

__device__ __forceinline__ u16 f2bf(float f) {
  union { float f; u32 u; } v; v.f = f;
  u32 r = (v.u + 0x7FFFu + ((v.u >> 16) & 1u)) >> 16;  // RNE
  return (u16)r;
}
__device__ __forceinline__ u32 pack2(float a, float b) {
  return (u32)f2bf(a) | ((u32)f2bf(b) << 16);
}

// ---------------- Kernel 0: proj (k-major fp32) -> projT[p][k] bf16 ----------------
__global__ __launch_bounds__(256) void transpose_proj(const float* __restrict__ proj,
                                                      u16* __restrict__ projT) {
  const int k = blockIdx.x;    // channel row: coalesced read
  const int p = threadIdx.x;   // projection col
  projT[(size_t)p * 256 + k] = f2bf(proj[(size_t)k * 256 + p]);
}

// ---------------- Kernel 1: xp_t[p][n] = sum_k proj[k][p] * x[n][k], bf16 MFMA ------
// Block tile: 128 p x 128 n; grid = 2 p-tiles (fast dim) x 1024 n-tiles.
__global__ __launch_bounds__(256) void gemm_xt(const float* __restrict__ x,
                                               const u16* __restrict__ projT,
                                               float* __restrict__ xp_t) {
  constexpr int LDT = 40;          // BK(32) + 8 pad (u16 units) -> 2-way-max banks
  __shared__ u16 As[128 * LDT];    // As[p][k]  (A[m][k], m=proj)
  __shared__ u16 Bs[128 * LDT];    // Bs[n][k]  (B[k][n], n=node)

  const int tid = threadIdx.x;
  const int bid = blockIdx.x;
  const int p0 = (bid & 1) * 128;   // p-tile fastest: the 2 blocks sharing an x tile are adjacent
  const int n0 = (bid >> 1) * 128;
  const int lane = tid & 63;
  const int w = tid >> 6;
  const int wp = (w >> 1) * 64;
  const int wn = (w & 1) * 64;
  const int quad = lane >> 4;
  const int m16 = lane & 15;
  const int row = tid >> 1;          // 0..127
  const int half = (tid & 1) * 16;   // 0 or 16 (k offset)

  f32x4 acc[4][4];
#pragma unroll
  for (int i = 0; i < 4; ++i)
#pragma unroll
    for (int j = 0; j < 4; ++j) acc[i][j] = (f32x4){0.f, 0.f, 0.f, 0.f};

  for (int k0 = 0; k0 < 256; k0 += 32) {
    // stage B: x[n0+row][k0+half .. +15] fp32 -> bf16
    const float* bsrc = x + (size_t)(n0 + row) * 256 + (k0 + half);
    float4 f0 = *(const float4*)(bsrc + 0);
    float4 f1 = *(const float4*)(bsrc + 4);
    float4 f2 = *(const float4*)(bsrc + 8);
    float4 f3 = *(const float4*)(bsrc + 12);
    // stage A: projT[p0+row][k0+half .. +15] already bf16 (32 B)
    const uint4* asrc = (const uint4*)(projT + (size_t)(p0 + row) * 256 + (k0 + half));
    uint4 a0 = asrc[0];
    uint4 a1 = asrc[1];
    uint4 b0 = { pack2(f0.x, f0.y), pack2(f0.z, f0.w), pack2(f1.x, f1.y), pack2(f1.z, f1.w) };
    uint4 b1 = { pack2(f2.x, f2.y), pack2(f2.z, f2.w), pack2(f3.x, f3.y), pack2(f3.z, f3.w) };
    *(uint4*)&Bs[row * LDT + half] = b0;
    *(uint4*)&Bs[row * LDT + half + 8] = b1;
    *(uint4*)&As[row * LDT + half] = a0;
    *(uint4*)&As[row * LDT + half + 8] = a1;
    __syncthreads();

    bf16x8 af[4], bfv[4];
#pragma unroll
    for (int mi = 0; mi < 4; ++mi)
      af[mi] = *(const bf16x8*)&As[(wp + mi * 16 + m16) * LDT + quad * 8];
#pragma unroll
    for (int ni = 0; ni < 4; ++ni)
      bfv[ni] = *(const bf16x8*)&Bs[(wn + ni * 16 + m16) * LDT + quad * 8];
#pragma unroll
    for (int mi = 0; mi < 4; ++mi)
#pragma unroll
      for (int ni = 0; ni < 4; ++ni)
        acc[mi][ni] = __builtin_amdgcn_mfma_f32_16x16x32_bf16(af[mi], bfv[ni], acc[mi][ni], 0, 0, 0);
    __syncthreads();
  }

  // epilogue: D row = m = quad*4 + reg, col = n = m16  -> xp_t[p][n]
#pragma unroll
  for (int mi = 0; mi < 4; ++mi) {
#pragma unroll
    for (int r = 0; r < 4; ++r) {
      const int p = p0 + wp + mi * 16 + quad * 4 + r;
      float* dst = xp_t + (size_t)p * 131072 + (n0 + wn + m16);
#pragma unroll
      for (int ni = 0; ni < 4; ++ni) dst[ni * 16] = acc[mi][ni][r];
    }
  }
}

// ---------------- Kernel 2: per-(g,p) sort of 512 + quantile select ----------------
// One wave per group: 8 regs/lane, element e = lane*8 + r. In-register bitonic:
// strides 1/2/4 intra-lane, strides 8..256 via shfl_xor (lane mask s/8).
// Block = 16 waves = 16 consecutive p of one graph -> 64B-coalesced output stores.
__global__ __launch_bounds__(1024) void sort_sel(const float* __restrict__ xp_t,
                                                 const float* __restrict__ cw,
                                                 float* __restrict__ out) {
  __shared__ float sbuf[16][516];  // 516 = 512 + 4 pad: 16B-aligned rows, 2-way-max banks
  const int tid = threadIdx.x;
  const int lane = tid & 63;
  const int w = tid >> 6;
  const int bid = blockIdx.x;
  const int g = bid >> 4;
  const int pt = bid & 15;
  const int p = pt * 16 + w;

  const float* src = xp_t + (size_t)p * 131072 + (size_t)g * 512;
  float4 lo4 = ((const float4*)src)[lane * 2];
  float4 hi4 = ((const float4*)src)[lane * 2 + 1];
  float v[8] = {lo4.x, lo4.y, lo4.z, lo4.w, hi4.x, hi4.y, hi4.z, hi4.w};

  // bitonic sort ascending, n=512. asc = ((e >> (k+1)) & 1) == 0.
  // e bits 0..2 = r, bits 3..8 = lane bits 0..5.
#pragma unroll
  for (int k = 0; k <= 8; ++k) {
#pragma unroll
    for (int j = k; j >= 0; --j) {
      if (j >= 3) {
        const int lm = 1 << (j - 3);
        const bool is_low = (lane & lm) == 0;
        const bool asc = (k == 8) ? true : (((lane >> (k - 2)) & 1) == 0);
        const bool take_min = (asc == is_low);
#pragma unroll
        for (int r = 0; r < 8; ++r) {
          float pv = __shfl_xor(v[r], lm, 64);
          float mn = fminf(v[r], pv), mx = fmaxf(v[r], pv);
          v[r] = take_min ? mn : mx;
        }
      } else {
        const int s = 1 << j;
        bool asc_lane = true;
        if (k >= 2 && k <= 7) asc_lane = (((lane >> (k - 2)) & 1) == 0);
#pragma unroll
        for (int r = 0; r < 8; ++r) {
          if ((r & s) == 0) {
            const int r2 = r | s;
            bool asc;
            if (k <= 1) asc = (((r >> (k + 1)) & 1) == 0);  // compile-time
            else asc = asc_lane;
            float a = v[r], b = v[r2];
            float mn = fminf(a, b), mx = fmaxf(a, b);
            v[r] = asc ? mn : mx;
            v[r2] = asc ? mx : mn;
          }
        }
      }
    }
  }

  // park sorted run in LDS
  *(float4*)&sbuf[w][lane * 8] = (float4){v[0], v[1], v[2], v[3]};
  *(float4*)&sbuf[w][lane * 8 + 4] = (float4){v[4], v[5], v[6], v[7]};
  __syncthreads();

  // selection: out[g][q][p] = sorted[idx[q]] / 256, idx[q] = floor(cw[q]*511)
  const float scale = 1.0f / 256.0f;
#pragma unroll
  for (int it = 0; it < 4; ++it) {
    const int linear = it * 1024 + tid;  // 0..4095
    const int q = linear >> 4;
    const int wp = linear & 15;
    const int iq = (int)floorf(cw[q] * 511.0f);
    const float val = sbuf[wp][iq];
    out[(size_t)g * 65536 + (size_t)q * 256 + pt * 16 + wp] = val * scale;
  }
}

extern "C" void kernel_launch(void* const* d_in, const int* in_sizes, int n_in,
                              void* d_out, int out_size, void* d_ws, size_t ws_size,
                              hipStream_t stream) {
  const float* x    = (const float*)d_in[0];  // (131072, 256) fp32
  const float* proj = (const float*)d_in[1];  // (256, 256) fp32
  const float* cw   = (const float*)d_in[2];  // (256,) fp32
  // d_in[3] = batch (unused: uniform arange//512), d_in[4] = num_graphs (256)
  float* out = (float*)d_out;                 // (256, 65536) fp32

  float* xp_t = (float*)d_ws;                                   // 128 MiB: xp_t[256][131072]
  u16* projT = (u16*)((char*)d_ws + (size_t)128 * 1024 * 1024); // 128 KiB: projT[256][256]

  transpose_proj<<<256, 256, 0, stream>>>(proj, projT);
  gemm_xt<<<2048, 256, 0, stream>>>(x, projT, xp_t);
  sort_sel<<<4096, 1024, 0, stream>>>(xp_t, cw, out);
}

// Round 2
// 365.016 us; speedup vs baseline: 1.0133x; 1.0133x over previous
//
#include <hip/hip_runtime.h>
#include <hip/hip_bf16.h>

typedef unsigned short u16;
typedef unsigned int u32;
typedef __bf16 bf16x8 __attribute__((ext_vector_type(8)));
typedef float f32x4 __attribute__((ext_vector_type(4)));

// N_NODES=131072, IN_CHANNELS=256, NUM_PROJ=256, NUM_QUANT=256, NUM_GRAPHS=256
// nodes_per_graph = 512; scale = sqrt(256*256) = 256.

__device__ __forceinline__ u16 f2bf(float f) {
  union { float f; u32 u; } v; v.f = f;
  u32 r = (v.u + 0x7FFFu + ((v.u >> 16) & 1u)) >> 16;  // RNE
  return (u16)r;
}
// pack two fp32 -> packed bf16 pair (a in low 16, b in high 16), RNE
__device__ __forceinline__ u32 pk_rne(float a, float b) {
  union { float f; u32 u; } va, vb; va.f = a; vb.f = b;
  u32 ra = (va.u + 0x7FFFu + ((va.u >> 16) & 1u)) >> 16;
  u32 rb = (vb.u + 0x7FFFu + ((vb.u >> 16) & 1u)) & 0xFFFF0000u;
  return rb | ra;
}

// async global->LDS, 16B per lane; lds base must be wave-uniform (lane scatter is +lane*16)
__device__ __forceinline__ void gl16(const void* g, void* l) {
  __builtin_amdgcn_global_load_lds((const __attribute__((address_space(1))) unsigned int*)g,
                                   (__attribute__((address_space(3))) unsigned int*)l,
                                   16, 0, 0);
}

// ---------------- Kernel 0: proj (k-major fp32) -> projT[p][k] bf16 ----------------
__global__ __launch_bounds__(256) void transpose_proj(const float* __restrict__ proj,
                                                      u16* __restrict__ projT) {
  const int k = blockIdx.x;    // channel row: coalesced read
  const int p = threadIdx.x;   // projection col
  projT[(size_t)p * 256 + k] = f2bf(proj[(size_t)k * 256 + p]);
}

// ---------------- Kernel 1: xp_t[p][n] = sum_k proj[k][p] * x[n][k] -----------------
// m97 structure: global_load_lds staging (A: bf16 projT, B: fp32 x), convert B at the
// ds_read->fragment step. Tile 128p x 128n, BK=32, 4 waves, 4x4 16x16x32 frags/wave.
__global__ __launch_bounds__(256) void gemm_xt(const float* __restrict__ x,
                                               const u16* __restrict__ projT,
                                               float* __restrict__ xp_t) {
  __shared__ u16 As[128 * 32];    // As[p][k] bf16, 64B rows, no pad (global_load_lds)
  __shared__ float Bs[128 * 32];  // Bs[n][k] fp32, 128B rows, no pad

  const int tid = threadIdx.x;
  const int bid = blockIdx.x;
  const int p0 = (bid & 1) * 128;   // p-tile fastest: blocks sharing an x tile are adjacent
  const int n0 = (bid >> 1) * 128;
  const int lane = tid & 63;
  const int w = tid >> 6;
  const int wp = (w >> 1) * 64;
  const int wn = (w & 1) * 64;
  const int quad = lane >> 4;
  const int m16 = lane & 15;

  // staging source addresses (k0 added per iter)
  // A chunks: this wave handles chunks 2w, 2w+1. chunk c: row p0+c*16+(lane>>2), k (lane&3)*8
  const u16* asrc0 = projT + (size_t)(p0 + (2 * w) * 16 + (lane >> 2)) * 256 + (lane & 3) * 8;
  const u16* asrc1 = asrc0 + 16 * 256;
  u16* adst0 = &As[(2 * w) * 512];   // 512 u16 = 1KB
  u16* adst1 = &As[(2 * w + 1) * 512];
  // B chunks: this wave handles chunks 4w..4w+3. chunk c: row n0+c*8+(lane>>3), col (lane&7)*4
  const float* bsrc0 = x + (size_t)(n0 + (4 * w) * 8 + (lane >> 3)) * 256 + (lane & 7) * 4;
  const float* bsrc1 = bsrc0 + 8 * 256;
  const float* bsrc2 = bsrc0 + 16 * 256;
  const float* bsrc3 = bsrc0 + 24 * 256;
  float* bdst0 = &Bs[(4 * w) * 256];  // 256 f32 = 1KB
  float* bdst1 = &Bs[(4 * w + 1) * 256];
  float* bdst2 = &Bs[(4 * w + 2) * 256];
  float* bdst3 = &Bs[(4 * w + 3) * 256];

  f32x4 acc[4][4];
#pragma unroll
  for (int i = 0; i < 4; ++i)
#pragma unroll
    for (int j = 0; j < 4; ++j) acc[i][j] = (f32x4){0.f, 0.f, 0.f, 0.f};

  for (int k0 = 0; k0 < 256; k0 += 32) {
    gl16(bsrc0 + k0, bdst0);
    gl16(bsrc1 + k0, bdst1);
    gl16(bsrc2 + k0, bdst2);
    gl16(bsrc3 + k0, bdst3);
    gl16(asrc0 + k0, adst0);
    gl16(asrc1 + k0, adst1);
    __syncthreads();  // drains vmcnt (global_load_lds) + lgkm

    bf16x8 af[4], bfv[4];
#pragma unroll
    for (int mi = 0; mi < 4; ++mi)
      af[mi] = *(const bf16x8*)&As[(wp + mi * 16 + m16) * 32 + quad * 8];
#pragma unroll
    for (int ni = 0; ni < 4; ++ni) {
      const float* bp = &Bs[(wn + ni * 16 + m16) * 32 + quad * 8];
      float4 f0 = *(const float4*)bp;
      float4 f1 = *(const float4*)(bp + 4);
      u32 pk[4] = { pk_rne(f0.x, f0.y), pk_rne(f0.z, f0.w),
                    pk_rne(f1.x, f1.y), pk_rne(f1.z, f1.w) };
      bfv[ni] = *(const bf16x8*)pk;
    }
#pragma unroll
    for (int mi = 0; mi < 4; ++mi)
#pragma unroll
      for (int ni = 0; ni < 4; ++ni)
        acc[mi][ni] = __builtin_amdgcn_mfma_f32_16x16x32_bf16(af[mi], bfv[ni], acc[mi][ni], 0, 0, 0);
    __syncthreads();
  }

  // epilogue: D row = m = quad*4 + reg, col = n = m16  -> xp_t[p][n]
#pragma unroll
  for (int mi = 0; mi < 4; ++mi) {
#pragma unroll
    for (int r = 0; r < 4; ++r) {
      const int p = p0 + wp + mi * 16 + quad * 4 + r;
      float* dst = xp_t + (size_t)p * 131072 + (n0 + wn + m16);
#pragma unroll
      for (int ni = 0; ni < 4; ++ni) dst[ni * 16] = acc[mi][ni][r];
    }
  }
}

// ---------------- Kernel 2: per-(g,p) sort of 512 + quantile select ----------------
// All-ascending flip-bitonic: merge level S does one flip pass (partner = e^(S-1)),
// then XOR passes S/4..1. Every CE is ascending: intra-lane = fmin/fmax (compile-time),
// cross-lane = cmp + mask-xnor + cndmask (2 VALU + 1 SALU per element).
// e = lane*8 + r. Block = 16 waves = 16 consecutive p of one graph.
__global__ __launch_bounds__(1024) void sort_sel(const float* __restrict__ xp_t,
                                                 const float* __restrict__ cw,
                                                 float* __restrict__ out) {
  __shared__ float sbuf[16][516];
  const int tid = threadIdx.x;
  const int lane = tid & 63;
  const int w = tid >> 6;
  const int bid = blockIdx.x;
  const int g = bid >> 4;
  const int pt = bid & 15;
  const int p = pt * 16 + w;

  const float* src = xp_t + (size_t)p * 131072 + (size_t)g * 512;
  float4 lo4 = ((const float4*)src)[lane * 2];
  float4 hi4 = ((const float4*)src)[lane * 2 + 1];
  float v[8] = {lo4.x, lo4.y, lo4.z, lo4.w, hi4.x, hi4.y, hi4.z, hi4.w};

#define CE(i, j) { float mn_ = fminf(v[i], v[j]); float mx_ = fmaxf(v[i], v[j]); v[i] = mn_; v[j] = mx_; }
#define INTRA3 \
  CE(0,4) CE(1,5) CE(2,6) CE(3,7) \
  CE(0,2) CE(1,3) CE(4,6) CE(5,7) \
  CE(0,1) CE(2,3) CE(4,5) CE(6,7)

#define FLIP(lm, lowbit) { \
    const bool low_ = (lane & (lowbit)) == 0; \
    _Pragma("unroll") \
    for (int rp = 0; rp < 4; ++rp) { \
      float a_ = v[rp], b_ = v[7 - rp]; \
      float pa_ = __shfl_xor(b_, (lm), 64); \
      float pb_ = __shfl_xor(a_, (lm), 64); \
      v[rp]     = ((pa_ < a_) == low_) ? pa_ : a_; \
      v[7 - rp] = ((pb_ < b_) == low_) ? pb_ : b_; \
    } }

#define XCROSS(lm) { \
    const bool low_ = (lane & (lm)) == 0; \
    _Pragma("unroll") \
    for (int r = 0; r < 8; ++r) { \
      float pv_ = __shfl_xor(v[r], (lm), 64); \
      v[r] = ((pv_ < v[r]) == low_) ? pv_ : v[r]; \
    } }

  // S=2
  CE(0,1) CE(2,3) CE(4,5) CE(6,7)
  // S=4
  CE(0,3) CE(1,2) CE(4,7) CE(5,6)
  CE(0,1) CE(2,3) CE(4,5) CE(6,7)
  // S=8
  CE(0,7) CE(1,6) CE(2,5) CE(3,4)
  CE(0,2) CE(1,3) CE(4,6) CE(5,7)
  CE(0,1) CE(2,3) CE(4,5) CE(6,7)
  // S=16
  FLIP(1, 1)  INTRA3
  // S=32
  FLIP(3, 2)  XCROSS(1)  INTRA3
  // S=64
  FLIP(7, 4)  XCROSS(2) XCROSS(1)  INTRA3
  // S=128
  FLIP(15, 8) XCROSS(4) XCROSS(2) XCROSS(1)  INTRA3
  // S=256
  FLIP(31, 16) XCROSS(8) XCROSS(4) XCROSS(2) XCROSS(1)  INTRA3
  // S=512
  FLIP(63, 32) XCROSS(16) XCROSS(8) XCROSS(4) XCROSS(2) XCROSS(1)  INTRA3

#undef CE
#undef INTRA3
#undef FLIP
#undef XCROSS

  // park sorted run in LDS
  *(float4*)&sbuf[w][lane * 8] = (float4){v[0], v[1], v[2], v[3]};
  *(float4*)&sbuf[w][lane * 8 + 4] = (float4){v[4], v[5], v[6], v[7]};
  __syncthreads();

  // selection: out[g][q][p] = sorted[idx[q]] / 256, idx[q] = floor(cw[q]*511)
  const float scale = 1.0f / 256.0f;
#pragma unroll
  for (int it = 0; it < 4; ++it) {
    const int linear = it * 1024 + tid;  // 0..4095
    const int q = linear >> 4;
    const int wp = linear & 15;
    const int iq = (int)floorf(cw[q] * 511.0f);
    const float val = sbuf[wp][iq];
    out[(size_t)g * 65536 + (size_t)q * 256 + pt * 16 + wp] = val * scale;
  }
}

extern "C" void kernel_launch(void* const* d_in, const int* in_sizes, int n_in,
                              void* d_out, int out_size, void* d_ws, size_t ws_size,
                              hipStream_t stream) {
  const float* x    = (const float*)d_in[0];  // (131072, 256) fp32
  const float* proj = (const float*)d_in[1];  // (256, 256) fp32
  const float* cw   = (const float*)d_in[2];  // (256,) fp32
  // d_in[3] = batch (unused: uniform arange//512), d_in[4] = num_graphs (256)
  float* out = (float*)d_out;                 // (256, 65536) fp32

  float* xp_t = (float*)d_ws;                                   // 128 MiB: xp_t[256][131072]
  u16* projT = (u16*)((char*)d_ws + (size_t)128 * 1024 * 1024); // 128 KiB: projT[256][256]

  transpose_proj<<<256, 256, 0, stream>>>(proj, projT);
  gemm_xt<<<2048, 256, 0, stream>>>(x, projT, xp_t);
  sort_sel<<<4096, 1024, 0, stream>>>(xp_t, cw, out);
}

// Round 3
// 286.705 us; speedup vs baseline: 1.2900x; 1.2731x over previous
//
#include <hip/hip_runtime.h>
#include <hip/hip_bf16.h>
#include <hip/hip_fp16.h>

typedef unsigned short u16;
typedef unsigned int u32;
typedef __bf16 bf16x8 __attribute__((ext_vector_type(8)));
typedef float f32x4 __attribute__((ext_vector_type(4)));
typedef u16 u16x8 __attribute__((ext_vector_type(8)));

// N_NODES=131072, IN_CHANNELS=256, NUM_PROJ=256, NUM_QUANT=256, NUM_GRAPHS=256
// nodes_per_graph = 512; scale = sqrt(256*256) = 256.

__device__ __forceinline__ u16 f2bf(float f) {
  union { float f; u32 u; } v; v.f = f;
  u32 r = (v.u + 0x7FFFu + ((v.u >> 16) & 1u)) >> 16;  // RNE
  return (u16)r;
}
// pack two fp32 -> packed bf16 pair (a low, b high), RNE
__device__ __forceinline__ u32 pk_rne(float a, float b) {
  union { float f; u32 u; } va, vb; va.f = a; vb.f = b;
  u32 ra = (va.u + 0x7FFFu + ((va.u >> 16) & 1u)) >> 16;
  u32 rb = (vb.u + 0x7FFFu + ((vb.u >> 16) & 1u)) & 0xFFFF0000u;
  return rb | ra;
}

// async global->LDS, 16B per lane; lds base wave-uniform, scatter = +lane*16
__device__ __forceinline__ void gl16(const void* g, void* l) {
  __builtin_amdgcn_global_load_lds((const __attribute__((address_space(1))) unsigned int*)g,
                                   (__attribute__((address_space(3))) unsigned int*)l,
                                   16, 0, 0);
}

// packed fp16 min/max (1 VOP3P each, both halves)
__device__ __forceinline__ u32 pkmin(u32 a, u32 b) {
  u32 r; asm("v_pk_min_f16 %0, %1, %2" : "=v"(r) : "v"(a), "v"(b)); return r;
}
__device__ __forceinline__ u32 pkmax(u32 a, u32 b) {
  u32 r; asm("v_pk_max_f16 %0, %1, %2" : "=v"(r) : "v"(a), "v"(b)); return r;
}

// cross-lane exchange: DPP (VALU pipe, free of DS) / ds_swizzle / bpermute
template <int CTRL> __device__ __forceinline__ u32 xdpp(u32 x) {
  return (u32)__builtin_amdgcn_mov_dpp((int)x, CTRL, 0xF, 0xF, true);
}
template <int IMM> __device__ __forceinline__ u32 xswz(u32 x) {
  return (u32)__builtin_amdgcn_ds_swizzle((int)x, IMM);
}
#define EX_X1(x)  xdpp<0xB1>(x)      /* quad_perm [1,0,3,2]  = xor 1  */
#define EX_X2(x)  xdpp<0x4E>(x)      /* quad_perm [2,3,0,1]  = xor 2  */
#define EX_F3(x)  xdpp<0x1B>(x)      /* quad_perm [3,2,1,0]  = xor 3  */
#define EX_F7(x)  xdpp<0x141>(x)     /* half_mirror          = xor 7  */
#define EX_F15(x) xdpp<0x140>(x)     /* row_mirror           = xor 15 */
#define EX_X8(x)  xdpp<0x128>(x)     /* row_ror:8            = xor 8  */
#define EX_X4(x)  xswz<0x101F>(x)    /* swizzle xor 4  */
#define EX_X16(x) xswz<0x401F>(x)    /* swizzle xor 16 */
#define EX_F31(x) xswz<0x7C1F>(x)    /* swizzle xor 31 */
#define EX_F63(x) ((u32)__shfl_xor((int)(x), 63, 64))

// ---------------- Kernel 0: proj (k-major fp32) -> projT[p][k] bf16 ----------------
__global__ __launch_bounds__(256) void transpose_proj(const float* __restrict__ proj,
                                                      u16* __restrict__ projT) {
  const int k = blockIdx.x;
  const int p = threadIdx.x;
  projT[(size_t)p * 256 + k] = f2bf(proj[(size_t)k * 256 + p]);
}

// ---------------- Kernel 1: xp16[p][n] = fp16(sum_k proj[k][p] * x[n][k]) -----------
__global__ __launch_bounds__(256) void gemm_xt(const float* __restrict__ x,
                                               const u16* __restrict__ projT,
                                               __half* __restrict__ xp16) {
  __shared__ u16 As[128 * 32];    // As[p][k] bf16
  __shared__ float Bs[128 * 32];  // Bs[n][k] fp32

  const int tid = threadIdx.x;
  const int bid = blockIdx.x;
  // XCD-aware swizzle: blocks b and b+8 share the same x n-tile and land on the
  // same XCD (bid%8) -> second block L2-hits the tile instead of refetching HBM.
  const int slot = bid & 7;
  const int j = bid >> 3;
  const int p0 = (j & 1) * 128;
  const int n0 = (slot + (j >> 1) * 8) * 128;
  const int lane = tid & 63;
  const int w = tid >> 6;
  const int wp = (w >> 1) * 64;
  const int wn = (w & 1) * 64;
  const int quad = lane >> 4;
  const int m16 = lane & 15;

  const u16* asrc0 = projT + (size_t)(p0 + (2 * w) * 16 + (lane >> 2)) * 256 + (lane & 3) * 8;
  const u16* asrc1 = asrc0 + 16 * 256;
  u16* adst0 = &As[(2 * w) * 512];
  u16* adst1 = &As[(2 * w + 1) * 512];
  const float* bsrc0 = x + (size_t)(n0 + (4 * w) * 8 + (lane >> 3)) * 256 + (lane & 7) * 4;
  const float* bsrc1 = bsrc0 + 8 * 256;
  const float* bsrc2 = bsrc0 + 16 * 256;
  const float* bsrc3 = bsrc0 + 24 * 256;
  float* bdst0 = &Bs[(4 * w) * 256];
  float* bdst1 = &Bs[(4 * w + 1) * 256];
  float* bdst2 = &Bs[(4 * w + 2) * 256];
  float* bdst3 = &Bs[(4 * w + 3) * 256];

  f32x4 acc[4][4];
#pragma unroll
  for (int i = 0; i < 4; ++i)
#pragma unroll
    for (int jj = 0; jj < 4; ++jj) acc[i][jj] = (f32x4){0.f, 0.f, 0.f, 0.f};

  for (int k0 = 0; k0 < 256; k0 += 32) {
    gl16(bsrc0 + k0, bdst0);
    gl16(bsrc1 + k0, bdst1);
    gl16(bsrc2 + k0, bdst2);
    gl16(bsrc3 + k0, bdst3);
    gl16(asrc0 + k0, adst0);
    gl16(asrc1 + k0, adst1);
    __syncthreads();

    bf16x8 af[4], bfv[4];
#pragma unroll
    for (int mi = 0; mi < 4; ++mi)
      af[mi] = *(const bf16x8*)&As[(wp + mi * 16 + m16) * 32 + quad * 8];
#pragma unroll
    for (int ni = 0; ni < 4; ++ni) {
      const float* bp = &Bs[(wn + ni * 16 + m16) * 32 + quad * 8];
      float4 f0 = *(const float4*)bp;
      float4 f1 = *(const float4*)(bp + 4);
      u32 pk[4] = { pk_rne(f0.x, f0.y), pk_rne(f0.z, f0.w),
                    pk_rne(f1.x, f1.y), pk_rne(f1.z, f1.w) };
      bfv[ni] = *(const bf16x8*)pk;
    }
#pragma unroll
    for (int mi = 0; mi < 4; ++mi)
#pragma unroll
      for (int ni = 0; ni < 4; ++ni)
        acc[mi][ni] = __builtin_amdgcn_mfma_f32_16x16x32_bf16(af[mi], bfv[ni], acc[mi][ni], 0, 0, 0);
    __syncthreads();
  }

  // epilogue: D row = m = quad*4 + reg, col = n = m16  -> xp16[p][n]
#pragma unroll
  for (int mi = 0; mi < 4; ++mi) {
#pragma unroll
    for (int r = 0; r < 4; ++r) {
      const int p = p0 + wp + mi * 16 + quad * 4 + r;
      __half* dst = xp16 + (size_t)p * 131072 + (n0 + wn + m16);
#pragma unroll
      for (int ni = 0; ni < 4; ++ni) dst[ni * 16] = __float2half(acc[mi][ni][r]);
    }
  }
}

// ---------------- Kernel 2: packed dual-group sort of 512 + quantile select --------
// Each wave sorts TWO groups at once: u32 reg = fp16 pair (lo = p, hi = p+16),
// compare-exchange via v_pk_min/max_f16. Cross-lane XOR 1/2/3/7/8/15 ride the VALU
// pipe as DPP; only XOR 4/16/31/63 touch the DS pipe (48 DS ops/wave vs 168).
__global__ __launch_bounds__(1024) void sort_sel(const __half* __restrict__ xp16,
                                                 const float* __restrict__ cw,
                                                 float* __restrict__ out) {
  __shared__ u32 sbuf[16][520];  // 520: 16B-aligned rows
  const int tid = threadIdx.x;
  const int lane = tid & 63;
  const int w = tid >> 6;
  const int bid = blockIdx.x;
  const int g = bid >> 3;
  const int pt = bid & 7;
  const int p_lo = pt * 32 + w;
  const int p_hi = p_lo + 16;

  const u16* slo = (const u16*)(xp16 + (size_t)p_lo * 131072 + (size_t)g * 512) + lane * 8;
  const u16* shi = (const u16*)(xp16 + (size_t)p_hi * 131072 + (size_t)g * 512) + lane * 8;
  u16x8 lo = *(const u16x8*)slo;
  u16x8 hi = *(const u16x8*)shi;
  u32 v[8];
#pragma unroll
  for (int r = 0; r < 8; ++r) v[r] = (u32)lo[r] | ((u32)hi[r] << 16);

#define CE(i, j) { u32 mn_ = pkmin(v[i], v[j]); u32 mx_ = pkmax(v[i], v[j]); v[i] = mn_; v[j] = mx_; }
#define INTRA3 \
  CE(0,4) CE(1,5) CE(2,6) CE(3,7) \
  CE(0,2) CE(1,3) CE(4,6) CE(5,7) \
  CE(0,1) CE(2,3) CE(4,5) CE(6,7)

#define FLIPP(EX, lowbit) { \
    const bool low_ = (lane & (lowbit)) == 0; \
    u32 t_[8]; \
    _Pragma("unroll") for (int r = 0; r < 8; ++r) t_[r] = EX(v[7 - r]); \
    _Pragma("unroll") for (int r = 0; r < 8; ++r) { \
      u32 mn_ = pkmin(v[r], t_[r]); u32 mx_ = pkmax(v[r], t_[r]); \
      v[r] = low_ ? mn_ : mx_; } }

#define XCROSSP(EX, lm) { \
    const bool low_ = (lane & (lm)) == 0; \
    _Pragma("unroll") for (int r = 0; r < 8; ++r) { \
      u32 t_ = EX(v[r]); \
      u32 mn_ = pkmin(v[r], t_); u32 mx_ = pkmax(v[r], t_); \
      v[r] = low_ ? mn_ : mx_; } }

  // S=2
  CE(0,1) CE(2,3) CE(4,5) CE(6,7)
  // S=4
  CE(0,3) CE(1,2) CE(4,7) CE(5,6)
  CE(0,1) CE(2,3) CE(4,5) CE(6,7)
  // S=8
  CE(0,7) CE(1,6) CE(2,5) CE(3,4)
  CE(0,2) CE(1,3) CE(4,6) CE(5,7)
  CE(0,1) CE(2,3) CE(4,5) CE(6,7)
  // S=16
  FLIPP(EX_X1, 1)  INTRA3
  // S=32
  FLIPP(EX_F3, 2)  XCROSSP(EX_X1, 1)  INTRA3
  // S=64
  FLIPP(EX_F7, 4)  XCROSSP(EX_X2, 2) XCROSSP(EX_X1, 1)  INTRA3
  // S=128
  FLIPP(EX_F15, 8) XCROSSP(EX_X4, 4) XCROSSP(EX_X2, 2) XCROSSP(EX_X1, 1)  INTRA3
  // S=256
  FLIPP(EX_F31, 16) XCROSSP(EX_X8, 8) XCROSSP(EX_X4, 4) XCROSSP(EX_X2, 2) XCROSSP(EX_X1, 1)  INTRA3
  // S=512
  FLIPP(EX_F63, 32) XCROSSP(EX_X16, 16) XCROSSP(EX_X8, 8) XCROSSP(EX_X4, 4) XCROSSP(EX_X2, 2) XCROSSP(EX_X1, 1)  INTRA3

#undef CE
#undef INTRA3
#undef FLIPP
#undef XCROSSP

  // park both sorted groups (packed) in LDS
  *(uint4*)&sbuf[w][lane * 8]     = (uint4){v[0], v[1], v[2], v[3]};
  *(uint4*)&sbuf[w][lane * 8 + 4] = (uint4){v[4], v[5], v[6], v[7]};
  __syncthreads();

  // selection: out[g][q][pt*32+pl] = sorted[idx[q]] / 256
  const float scale = 1.0f / 256.0f;
#pragma unroll
  for (int it = 0; it < 8; ++it) {
    const int linear = it * 1024 + tid;  // 0..8191
    const int q = linear >> 5;
    const int pl = linear & 31;
    const int iq = (int)floorf(cw[q] * 511.0f);
    const u32 val = sbuf[pl & 15][iq];
    const u16 h = (pl & 16) ? (u16)(val >> 16) : (u16)(val & 0xFFFF);
    __half_raw hr; hr.x = h;
    out[(size_t)g * 65536 + (size_t)q * 256 + pt * 32 + pl] = __half2float(__half(hr)) * scale;
  }
}

extern "C" void kernel_launch(void* const* d_in, const int* in_sizes, int n_in,
                              void* d_out, int out_size, void* d_ws, size_t ws_size,
                              hipStream_t stream) {
  const float* x    = (const float*)d_in[0];  // (131072, 256) fp32
  const float* proj = (const float*)d_in[1];  // (256, 256) fp32
  const float* cw   = (const float*)d_in[2];  // (256,) fp32
  float* out = (float*)d_out;                 // (256, 65536) fp32

  __half* xp16 = (__half*)d_ws;                                 // 64 MiB: xp16[256][131072]
  u16* projT = (u16*)((char*)d_ws + (size_t)64 * 1024 * 1024);  // 128 KiB

  transpose_proj<<<256, 256, 0, stream>>>(proj, projT);
  gemm_xt<<<2048, 256, 0, stream>>>(x, projT, xp16);
  sort_sel<<<2048, 1024, 0, stream>>>(xp16, cw, out);
}